// Round 2
// baseline (1421.355 us; speedup 1.0000x reference)
//
#include <hip/hip_runtime.h>
#include <hip/hip_bf16.h>

// Shapes (fixed by the reference):
#define BB 128
#define FF 64
#define AA 64
#define TT 512

// exp2-domain pre-scales (folded into z and W_hh so the scan's dependent
// chain is fmaf -> v_exp_f32 -> v_add -> v_rcp_f32 -> fmaf with no extra muls)
#define S_SIG  (-1.4426950408889634f)   // -log2(e): sigmoid(v) = rcp(1+exp2(-log2e*v))
#define S_TANH ( 2.8853900817779268f)   //  2*log2(e): tanh(v) = 1-2*rcp(1+exp2(2log2e*v))
#define K_IG   ( 2.8853900817779268f)   //  c2 = 2log2e*c domain scale for i*g

// ---------------------------------------------------------------------------
// Kernel 1: z[cell][t][g] = scale_g * (sum_f x[b][f][a][t]*W_ih[g][f] + bias[a][g])
//   cell = b*64+a. One block (128 thr) per cell; thread -> 4 consecutive t
//   (float4 loads, 16B/lane). Bias and exp2-domain scales folded in here so
//   the scan kernel's serial chain is minimal.
// ---------------------------------------------------------------------------
__global__ __launch_bounds__(128) void k_zgemm(const float* __restrict__ x,
                                               const float* __restrict__ W_ih,
                                               const float* __restrict__ b_ih,
                                               const float* __restrict__ b_hh,
                                               float4* __restrict__ z) {
    __shared__ float4 wlds[FF];  // wlds[f] = {W[0][f],W[1][f],W[2][f],W[3][f]}
    const int tid = threadIdx.x;
    if (tid < FF) {
        wlds[tid] = make_float4(W_ih[0 * 128 + tid], W_ih[1 * 128 + tid],
                                W_ih[2 * 128 + tid], W_ih[3 * 128 + tid]);
    }
    __syncthreads();

    const int cell = blockIdx.x;
    const int b = cell >> 6;
    const int a = cell & 63;

    // x[b][f][a][t]: base at f=0, plane stride AA*TT floats (128 KB)
    const float* xp = x + (size_t)b * (FF * AA * TT) + (size_t)a * TT + 4 * tid;

    float4 acc0 = {0.f, 0.f, 0.f, 0.f};
    float4 acc1 = {0.f, 0.f, 0.f, 0.f};
    float4 acc2 = {0.f, 0.f, 0.f, 0.f};
    float4 acc3 = {0.f, 0.f, 0.f, 0.f};

#pragma unroll 16
    for (int f = 0; f < FF; ++f) {
        const float4 xv = *reinterpret_cast<const float4*>(xp + (size_t)f * (AA * TT));
        const float4 w = wlds[f];
        acc0.x = fmaf(xv.x, w.x, acc0.x); acc0.y = fmaf(xv.x, w.y, acc0.y);
        acc0.z = fmaf(xv.x, w.z, acc0.z); acc0.w = fmaf(xv.x, w.w, acc0.w);
        acc1.x = fmaf(xv.y, w.x, acc1.x); acc1.y = fmaf(xv.y, w.y, acc1.y);
        acc1.z = fmaf(xv.y, w.z, acc1.z); acc1.w = fmaf(xv.y, w.w, acc1.w);
        acc2.x = fmaf(xv.z, w.x, acc2.x); acc2.y = fmaf(xv.z, w.y, acc2.y);
        acc2.z = fmaf(xv.z, w.z, acc2.z); acc2.w = fmaf(xv.z, w.w, acc2.w);
        acc3.x = fmaf(xv.w, w.x, acc3.x); acc3.y = fmaf(xv.w, w.y, acc3.y);
        acc3.z = fmaf(xv.w, w.z, acc3.z); acc3.w = fmaf(xv.w, w.w, acc3.w);
    }

    // per-(a,g) bias (block-uniform -> scalar loads), then exp2-domain scale
    const float bi = W_ih[0 * 128 + FF + a] + b_ih[0] + b_hh[0];
    const float bf = W_ih[1 * 128 + FF + a] + b_ih[1] + b_hh[1];
    const float bg = W_ih[2 * 128 + FF + a] + b_ih[2] + b_hh[2];
    const float bo = W_ih[3 * 128 + FF + a] + b_ih[3] + b_hh[3];

#define SCALE4(A)                                         \
    A.x = (A.x + bi) * S_SIG;  A.y = (A.y + bf) * S_SIG;  \
    A.z = (A.z + bg) * S_TANH; A.w = (A.w + bo) * S_SIG;
    SCALE4(acc0) SCALE4(acc1) SCALE4(acc2) SCALE4(acc3)
#undef SCALE4

    float4* zp = z + (size_t)cell * TT + 4 * tid;
    zp[0] = acc0; zp[1] = acc1; zp[2] = acc2; zp[3] = acc3;
}

// ---------------------------------------------------------------------------
// Kernel 2: per-cell LSTM scan over T=512 + fused wave-wide softmax over a.
//   128 blocks x 64 threads: blockIdx = b, lane = a. One wave per block so
//   128 CUs each run one independent serial chain with deep prefetch.
// ---------------------------------------------------------------------------
__device__ __forceinline__ float rcp_f(float v) { return __builtin_amdgcn_rcpf(v); }
__device__ __forceinline__ float ex2_f(float v) { return __builtin_amdgcn_exp2f(v); }

// zt gates are pre-scaled: x,y,w = -log2e*(pre); z = 2log2e*(pre).
// c2 = 2log2e * c.
__device__ __forceinline__ void lstm_step(const float4 zt, const float4 wh2,
                                          float& h, float& c2) {
    const float pi = fmaf(h, wh2.x, zt.x);
    const float pf = fmaf(h, wh2.y, zt.y);
    const float pg = fmaf(h, wh2.z, zt.z);
    const float po = fmaf(h, wh2.w, zt.w);
    const float iK = K_IG * rcp_f(1.f + ex2_f(pi));           // 2log2e * sigmoid(gi)
    const float f  = rcp_f(1.f + ex2_f(pf));                  // sigmoid(gf)
    const float g  = fmaf(-2.f, rcp_f(1.f + ex2_f(pg)), 1.f); // tanh(gg)
    const float o  = rcp_f(1.f + ex2_f(po));                  // sigmoid(go)
    c2 = fmaf(f, c2, iK * g);
    const float th = fmaf(-2.f, rcp_f(1.f + ex2_f(c2)), 1.f); // tanh(c)
    h = o * th;
}

__global__ __launch_bounds__(64) void k_scan(const float4* __restrict__ z,
                                             const float* __restrict__ W_hh,
                                             float* __restrict__ out) {
    const int a = threadIdx.x;  // lane = a -> softmax over A is wave-local
    const int b = blockIdx.x;
    const float4* zp = z + (size_t)((b << 6) | a) * TT;

    const float4 wh2 = make_float4(S_SIG * W_hh[0], S_SIG * W_hh[1],
                                   S_TANH * W_hh[2], S_SIG * W_hh[3]);

    float h = 0.f, c2 = 0.f;

    // 4-deep rolling chunk prefetch (chunk = 4 timesteps = 64B/lane, so
    // 256B/lane = 16KB/wave in flight). All buffers statically indexed.
    float4 q0a = zp[0],  q0b = zp[1],  q0c = zp[2],  q0d = zp[3];
    float4 q1a = zp[4],  q1b = zp[5],  q1c = zp[6],  q1d = zp[7];
    float4 q2a = zp[8],  q2b = zp[9],  q2c = zp[10], q2d = zp[11];
    float4 q3a = zp[12], q3b = zp[13], q3c = zp[14], q3d = zp[15];

#define PHASE(Q, OFF)                                                      \
    {                                                                      \
        const float4 t0 = Q##a, t1 = Q##b, t2 = Q##c, t3 = Q##d;           \
        const int pf = ((ch + (OFF) < 128) ? (ch + (OFF)) : 127) * 4;      \
        Q##a = zp[pf + 0]; Q##b = zp[pf + 1];                              \
        Q##c = zp[pf + 2]; Q##d = zp[pf + 3];                              \
        lstm_step(t0, wh2, h, c2); lstm_step(t1, wh2, h, c2);              \
        lstm_step(t2, wh2, h, c2); lstm_step(t3, wh2, h, c2);              \
    }

    for (int ch = 0; ch < 128; ch += 4) {
        PHASE(q0, 4)
        PHASE(q1, 5)
        PHASE(q2, 6)
        PHASE(q3, 7)
    }
#undef PHASE

    // softmax over the 64 lanes (axis A), out[b][a]
    float m = h;
#pragma unroll
    for (int off = 32; off > 0; off >>= 1) m = fmaxf(m, __shfl_xor(m, off, 64));
    const float e = __expf(h - m);
    float s = e;
#pragma unroll
    for (int off = 32; off > 0; off >>= 1) s += __shfl_xor(s, off, 64);
    out[(b << 6) | a] = __fdividef(e, s);
}

// ---------------------------------------------------------------------------
extern "C" void kernel_launch(void* const* d_in, const int* in_sizes, int n_in,
                              void* d_out, int out_size, void* d_ws, size_t ws_size,
                              hipStream_t stream) {
    const float* x    = (const float*)d_in[0];
    const float* W_ih = (const float*)d_in[1];
    const float* W_hh = (const float*)d_in[2];
    const float* b_ih = (const float*)d_in[3];
    const float* b_hh = (const float*)d_in[4];
    float* out = (float*)d_out;

    float4* z = (float4*)d_ws;  // 8192 cells * 512 t * 16B = 64 MiB scratch

    hipLaunchKernelGGL(k_zgemm, dim3(BB * AA), dim3(128), 0, stream,
                       x, W_ih, b_ih, b_hh, z);
    hipLaunchKernelGGL(k_scan, dim3(BB), dim3(64), 0, stream, z, W_hh, out);
}